// Round 1
// baseline (247.669 us; speedup 1.0000x reference)
//
#include <hip/hip_runtime.h>

// DropNorm: B=4096 rows, F=8192 features, fp32.
//   n = F/2 (mask has exactly F/2 ones)
//   mu = sum(x*m)/n ; sigma2 = sum(((x-mu)*m)^2)/(n-1)
//   out = gamma * ((x-mu)*m) * rsqrt(sigma2^2 + 1e-4) + beta   [sigma2 SQUARED: quirk]
// Memory-bound: read x once (rows held in registers), write out once.

constexpr int Bn = 4096;
constexpr int Fn = 8192;
constexpr int NT = 256;          // threads per block
constexpr int PT = Fn / (NT * 4); // 8 float4 per thread

#define EPSV 1e-4f

// Prep: detect mask storage layout (uint8 bool vs int32) and materialize
//   m01[j] = mask ? 1.0 : 0.0
//   mg[j]  = mask ? gamma[j] : 0.0
// Detection: count nonzero among the first Fn BYTES. uint8 layout -> exactly
// Fn/2 = 4096 (mask has exactly half ones). int32 layout -> those bytes span
// only 2048 ints, so count <= 2048. Unambiguous.
__global__ __launch_bounds__(NT) void prep_kernel(const void* __restrict__ mask_raw,
                                                  const float* __restrict__ gamma,
                                                  float* __restrict__ m01,
                                                  float* __restrict__ mg) {
    const unsigned char* mb = (const unsigned char*)mask_raw;
    const int* mi = (const int*)mask_raw;
    const int tid = threadIdx.x;

    int cnt = 0;
    for (int j = tid; j < Fn; j += NT) cnt += (mb[j] != 0) ? 1 : 0;
    for (int off = 32; off > 0; off >>= 1) cnt += __shfl_down(cnt, off, 64);

    __shared__ int wc[NT / 64];
    __shared__ int flag;
    if ((tid & 63) == 0) wc[tid >> 6] = cnt;
    __syncthreads();
    if (tid == 0) {
        int total = wc[0] + wc[1] + wc[2] + wc[3];
        flag = (total == Fn / 2) ? 1 : 0;   // 1 = uint8 layout, 0 = int32 layout
    }
    __syncthreads();
    const bool u8 = (flag != 0);

    const int per_block = Fn / gridDim.x;
    const int base = blockIdx.x * per_block;
    for (int j = base + tid; j < base + per_block; j += NT) {
        const bool on = u8 ? (mb[j] != 0) : (mi[j] != 0);
        m01[j] = on ? 1.0f : 0.0f;
        mg[j]  = on ? gamma[j] : 0.0f;
    }
}

__global__ __launch_bounds__(NT) void dropnorm_kernel(const float* __restrict__ x,
                                                      const float* __restrict__ m01,
                                                      const float* __restrict__ mg,
                                                      const float* __restrict__ beta,
                                                      float* __restrict__ out) {
    const int row = blockIdx.x;
    const int tid = threadIdx.x;

    const float4* __restrict__ xr  = (const float4*)(x + (size_t)row * Fn);
    const float4* __restrict__ m4  = (const float4*)m01;
    const float4* __restrict__ mg4 = (const float4*)mg;
    const float4* __restrict__ b4  = (const float4*)beta;
    float4* __restrict__ o4        = (float4*)(out + (size_t)row * Fn);

    float4 v[PT];
    float s = 0.f, ss = 0.f;

#pragma unroll
    for (int k = 0; k < PT; ++k) {
        const int idx = tid + k * NT;           // coalesced float4 access
        const float4 xv = xr[idx];
        const float4 mv = m4[idx];
        v[k] = xv;
        const float a0 = xv.x * mv.x;
        const float a1 = xv.y * mv.y;
        const float a2 = xv.z * mv.z;
        const float a3 = xv.w * mv.w;
        s  += (a0 + a1) + (a2 + a3);
        ss += (a0 * a0 + a1 * a1) + (a2 * a2 + a3 * a3);
    }

    // wave (64-lane) shuffle reduction, then cross-wave via LDS
    for (int off = 32; off > 0; off >>= 1) {
        s  += __shfl_down(s, off, 64);
        ss += __shfl_down(ss, off, 64);
    }
    __shared__ float rs[NT / 64], rss[NT / 64];
    if ((tid & 63) == 0) { rs[tid >> 6] = s; rss[tid >> 6] = ss; }
    __syncthreads();
    const float S  = (rs[0] + rs[1]) + (rs[2] + rs[3]);
    const float SS = (rss[0] + rss[1]) + (rss[2] + rss[3]);

    const float n  = (float)(Fn / 2);
    const float mu = S / n;
    // sum(diff^2) = sum(x^2 m) - n*mu^2   (since sum(m) == n exactly)
    const float sigma2 = (SS - n * mu * mu) / (n - 1.0f);
    const float inv = rsqrtf(sigma2 * sigma2 + EPSV);  // quirk: sigma2 squared

#pragma unroll
    for (int k = 0; k < PT; ++k) {
        const int idx = tid + k * NT;
        const float4 g  = mg4[idx];
        const float4 bt = b4[idx];
        const float4 xv = v[k];
        float4 o;
        o.x = g.x * (xv.x - mu) * inv + bt.x;
        o.y = g.y * (xv.y - mu) * inv + bt.y;
        o.z = g.z * (xv.z - mu) * inv + bt.z;
        o.w = g.w * (xv.w - mu) * inv + bt.w;
        o4[idx] = o;
    }
}

extern "C" void kernel_launch(void* const* d_in, const int* in_sizes, int n_in,
                              void* d_out, int out_size, void* d_ws, size_t ws_size,
                              hipStream_t stream) {
    const float* x     = (const float*)d_in[0];
    const float* gamma = (const float*)d_in[1];
    const float* beta  = (const float*)d_in[2];
    const void*  mask  = d_in[3];
    float* out = (float*)d_out;

    float* m01 = (float*)d_ws;       // Fn floats
    float* mg  = m01 + Fn;           // Fn floats

    prep_kernel<<<16, NT, 0, stream>>>(mask, gamma, m01, mg);
    dropnorm_kernel<<<Bn, NT, 0, stream>>>(x, m01, mg, beta, out);
}

// Round 2
// 246.325 us; speedup vs baseline: 1.0055x; 1.0055x over previous
//
#include <hip/hip_runtime.h>

// DropNorm: B=4096 rows, F=8192 features, fp32.
//   n = F/2; mu = sum(x*m)/n; sigma2 = sum(((x-mu)*m)^2)/(n-1)
//   out = gamma*m*(x-mu)*rsqrt(sigma2^2 + 1e-4) + beta   [sigma2 SQUARED: quirk]
//
// R2: latency-bound fix. R1 showed VGPR_Count=32 -> compiler refused to hold
// the 32-float row in registers and re-loaded x in the epilogue (load-use
// stalls, 8% VALUBusy, 2.5 TB/s). Stage the row in LDS instead: tiny per-thread
// register state, all global loads in flight, epilogue reads from LDS.

constexpr int Bn = 4096;
constexpr int Fn = 8192;
constexpr int NT = 256;           // threads per block
constexpr int PT = Fn / (NT * 4); // 8 float4 per thread

typedef float f4 __attribute__((ext_vector_type(4)));

#define EPSV 1e-4f

// Prep: detect mask storage layout (uint8 bool vs int32) and materialize
//   m01[j] = mask ? 1.0 : 0.0 ;  mg[j] = mask ? gamma[j] : 0.0
// Detection: count nonzero among the first Fn BYTES. uint8 layout -> exactly
// Fn/2 = 4096; int32 layout -> those bytes span only 2048 ints -> count <= 2048.
__global__ __launch_bounds__(NT) void prep_kernel(const void* __restrict__ mask_raw,
                                                  const float* __restrict__ gamma,
                                                  float* __restrict__ m01,
                                                  float* __restrict__ mg) {
    const unsigned char* mb = (const unsigned char*)mask_raw;
    const int* mi = (const int*)mask_raw;
    const int tid = threadIdx.x;

    int cnt = 0;
    for (int j = tid; j < Fn; j += NT) cnt += (mb[j] != 0) ? 1 : 0;
    for (int off = 32; off > 0; off >>= 1) cnt += __shfl_down(cnt, off, 64);

    __shared__ int wc[NT / 64];
    __shared__ int flag;
    if ((tid & 63) == 0) wc[tid >> 6] = cnt;
    __syncthreads();
    if (tid == 0) {
        int total = wc[0] + wc[1] + wc[2] + wc[3];
        flag = (total == Fn / 2) ? 1 : 0;   // 1 = uint8 layout, 0 = int32 layout
    }
    __syncthreads();
    const bool u8 = (flag != 0);

    const int per_block = Fn / gridDim.x;
    const int base = blockIdx.x * per_block;
    for (int j = base + tid; j < base + per_block; j += NT) {
        const bool on = u8 ? (mb[j] != 0) : (mi[j] != 0);
        m01[j] = on ? 1.0f : 0.0f;
        mg[j]  = on ? gamma[j] : 0.0f;
    }
}

__global__ __launch_bounds__(NT) void dropnorm_kernel(const float* __restrict__ x,
                                                      const float* __restrict__ m01,
                                                      const float* __restrict__ mg,
                                                      const float* __restrict__ beta,
                                                      float* __restrict__ out) {
    __shared__ f4 srow[Fn / 4];            // 32 KB: the staged row
    __shared__ float rs[NT / 64], rss[NT / 64];

    const int row = blockIdx.x;
    const int tid = threadIdx.x;

    const f4* __restrict__ xr  = (const f4*)(x + (size_t)row * Fn);
    const f4* __restrict__ m4  = (const f4*)m01;
    const f4* __restrict__ mg4 = (const f4*)mg;
    const f4* __restrict__ b4  = (const f4*)beta;
    f4* __restrict__ o4        = (f4*)(out + (size_t)row * Fn);

    float s = 0.f, ss = 0.f;

#pragma unroll
    for (int k = 0; k < PT; ++k) {
        const int idx = tid + k * NT;                     // coalesced
        const f4 xv = __builtin_nontemporal_load(xr + idx); // x read exactly once
        const f4 mv = m4[idx];                            // L2-broadcast
        srow[idx] = xv;                                   // stage row in LDS
        const float a0 = xv.x * mv.x;
        const float a1 = xv.y * mv.y;
        const float a2 = xv.z * mv.z;
        const float a3 = xv.w * mv.w;
        s  += (a0 + a1) + (a2 + a3);
        ss += (a0 * a0 + a1 * a1) + (a2 * a2 + a3 * a3);
    }

    // 64-lane shuffle reduction, then cross-wave via LDS
    for (int off = 32; off > 0; off >>= 1) {
        s  += __shfl_down(s, off, 64);
        ss += __shfl_down(ss, off, 64);
    }
    if ((tid & 63) == 0) { rs[tid >> 6] = s; rss[tid >> 6] = ss; }
    __syncthreads();   // also covers srow visibility (each thread re-reads own slots anyway)
    const float S  = (rs[0] + rs[1]) + (rs[2] + rs[3]);
    const float SS = (rss[0] + rss[1]) + (rss[2] + rss[3]);

    const float n  = (float)(Fn / 2);
    const float mu = S / n;
    // sum(diff^2) = sum(x^2 m) - n*mu^2   (sum(m) == n exactly)
    const float sigma2 = (SS - n * mu * mu) / (n - 1.0f);
    const float inv = rsqrtf(sigma2 * sigma2 + EPSV);  // quirk: sigma2 squared

#pragma unroll
    for (int k = 0; k < PT; ++k) {
        const int idx = tid + k * NT;
        const f4 xv = srow[idx];       // LDS read, dense b128, conflict-free
        const f4 g  = mg4[idx];
        const f4 bt = b4[idx];
        f4 o;
        o.x = g.x * (xv.x - mu) * inv + bt.x;
        o.y = g.y * (xv.y - mu) * inv + bt.y;
        o.z = g.z * (xv.z - mu) * inv + bt.z;
        o.w = g.w * (xv.w - mu) * inv + bt.w;
        __builtin_nontemporal_store(o, o4 + idx);  // out written once, never read
    }
}

extern "C" void kernel_launch(void* const* d_in, const int* in_sizes, int n_in,
                              void* d_out, int out_size, void* d_ws, size_t ws_size,
                              hipStream_t stream) {
    const float* x     = (const float*)d_in[0];
    const float* gamma = (const float*)d_in[1];
    const float* beta  = (const float*)d_in[2];
    const void*  mask  = d_in[3];
    float* out = (float*)d_out;

    float* m01 = (float*)d_ws;       // Fn floats
    float* mg  = m01 + Fn;           // Fn floats

    prep_kernel<<<16, NT, 0, stream>>>(mask, gamma, m01, mg);
    dropnorm_kernel<<<Bn, NT, 0, stream>>>(x, m01, mg, beta, out);
}

// Round 3
// 244.482 us; speedup vs baseline: 1.0130x; 1.0075x over previous
//
#include <hip/hip_runtime.h>

// DropNorm: B=4096 rows, F=8192 features, fp32.
//   n = F/2; mu = sum(x*m)/n; sigma2 = sum(((x-mu)*m)^2)/(n-1)
//   out = gamma*m*(x-mu)*rsqrt(sigma2^2 + 1e-4) + beta   [sigma2 SQUARED: quirk]
//
// R3: force memory-level parallelism. R1 showed VGPR_Count=32 -> loads were
// issued in tiny batches with a full memory latency each (2.5 TB/s, VALU 8%).
// Fix: __launch_bounds__(256,4) (VGPR cap 128) + explicit load-all-then-use
// register arrays so all 16 global_load_dwordx4 are in flight before the
// first s_waitcnt. LDS staging keeps the epilogue off the global path.

constexpr int Bn = 4096;
constexpr int Fn = 8192;
constexpr int NT = 256;           // threads per block
constexpr int PT = Fn / (NT * 4); // 8 float4 per thread

typedef float f4 __attribute__((ext_vector_type(4)));

#define EPSV 1e-4f

// Prep: detect mask storage layout (uint8 bool vs int32) and materialize
//   m01[j] = mask ? 1.0 : 0.0 ;  mg[j] = mask ? gamma[j] : 0.0
// Detection: count nonzero among the first Fn BYTES. uint8 layout -> exactly
// Fn/2 = 4096; int32 layout -> those bytes span only 2048 ints -> count <= 2048.
__global__ __launch_bounds__(NT) void prep_kernel(const void* __restrict__ mask_raw,
                                                  const float* __restrict__ gamma,
                                                  float* __restrict__ m01,
                                                  float* __restrict__ mg) {
    const unsigned char* mb = (const unsigned char*)mask_raw;
    const int* mi = (const int*)mask_raw;
    const int tid = threadIdx.x;

    int cnt = 0;
    for (int j = tid; j < Fn; j += NT) cnt += (mb[j] != 0) ? 1 : 0;
    for (int off = 32; off > 0; off >>= 1) cnt += __shfl_down(cnt, off, 64);

    __shared__ int wc[NT / 64];
    __shared__ int flag;
    if ((tid & 63) == 0) wc[tid >> 6] = cnt;
    __syncthreads();
    if (tid == 0) {
        int total = wc[0] + wc[1] + wc[2] + wc[3];
        flag = (total == Fn / 2) ? 1 : 0;   // 1 = uint8 layout, 0 = int32 layout
    }
    __syncthreads();
    const bool u8 = (flag != 0);

    const int per_block = Fn / gridDim.x;
    const int base = blockIdx.x * per_block;
    for (int j = base + tid; j < base + per_block; j += NT) {
        const bool on = u8 ? (mb[j] != 0) : (mi[j] != 0);
        m01[j] = on ? 1.0f : 0.0f;
        mg[j]  = on ? gamma[j] : 0.0f;
    }
}

__global__ __launch_bounds__(NT, 4) void dropnorm_kernel(const float* __restrict__ x,
                                                         const float* __restrict__ m01,
                                                         const float* __restrict__ mg,
                                                         const float* __restrict__ beta,
                                                         float* __restrict__ out) {
    __shared__ f4 srow[Fn / 4];            // 32 KB: the staged row
    __shared__ float rs[NT / 64], rss[NT / 64];

    const int row = blockIdx.x;
    const int tid = threadIdx.x;

    const f4* __restrict__ xr  = (const f4*)(x + (size_t)row * Fn);
    const f4* __restrict__ m4  = (const f4*)m01;
    const f4* __restrict__ mg4 = (const f4*)mg;
    const f4* __restrict__ b4  = (const f4*)beta;
    f4* __restrict__ o4        = (f4*)(out + (size_t)row * Fn);

    // ---- phase 1: issue ALL global loads back-to-back into register arrays
    f4 xv[PT];
    f4 mv[PT];
#pragma unroll
    for (int k = 0; k < PT; ++k) xv[k] = xr[tid + k * NT];   // 8 dwordx4, coalesced
#pragma unroll
    for (int k = 0; k < PT; ++k) mv[k] = m4[tid + k * NT];   // 8 dwordx4, L1/L2-hot

    // ---- phase 2: stage row to LDS + accumulate (loads already in flight)
    float s = 0.f, ss = 0.f;
#pragma unroll
    for (int k = 0; k < PT; ++k) {
        srow[tid + k * NT] = xv[k];
        const float a0 = xv[k].x * mv[k].x;
        const float a1 = xv[k].y * mv[k].y;
        const float a2 = xv[k].z * mv[k].z;
        const float a3 = xv[k].w * mv[k].w;
        s  += (a0 + a1) + (a2 + a3);
        ss += (a0 * a0 + a1 * a1) + (a2 * a2 + a3 * a3);
    }

    // 64-lane shuffle reduction, then cross-wave via LDS
    for (int off = 32; off > 0; off >>= 1) {
        s  += __shfl_down(s, off, 64);
        ss += __shfl_down(ss, off, 64);
    }
    if ((tid & 63) == 0) { rs[tid >> 6] = s; rss[tid >> 6] = ss; }
    __syncthreads();
    const float S  = (rs[0] + rs[1]) + (rs[2] + rs[3]);
    const float SS = (rss[0] + rss[1]) + (rss[2] + rss[3]);

    const float n  = (float)(Fn / 2);
    const float mu = S / n;
    // sum(diff^2) = sum(x^2 m) - n*mu^2   (sum(m) == n exactly)
    const float sigma2 = (SS - n * mu * mu) / (n - 1.0f);
    const float inv = rsqrtf(sigma2 * sigma2 + EPSV);  // quirk: sigma2 squared

    // ---- epilogue: load-all (mg, beta) then compute+store from LDS row
    f4 gv[PT];
    f4 bv[PT];
#pragma unroll
    for (int k = 0; k < PT; ++k) gv[k] = mg4[tid + k * NT];
#pragma unroll
    for (int k = 0; k < PT; ++k) bv[k] = b4[tid + k * NT];

#pragma unroll
    for (int k = 0; k < PT; ++k) {
        const int idx = tid + k * NT;
        const f4 xs = srow[idx];       // dense ds_read_b128, conflict-free
        f4 o;
        o.x = gv[k].x * (xs.x - mu) * inv + bv[k].x;
        o.y = gv[k].y * (xs.y - mu) * inv + bv[k].y;
        o.z = gv[k].z * (xs.z - mu) * inv + bv[k].z;
        o.w = gv[k].w * (xs.w - mu) * inv + bv[k].w;
        __builtin_nontemporal_store(o, o4 + idx);  // out written once, never read
    }
}

extern "C" void kernel_launch(void* const* d_in, const int* in_sizes, int n_in,
                              void* d_out, int out_size, void* d_ws, size_t ws_size,
                              hipStream_t stream) {
    const float* x     = (const float*)d_in[0];
    const float* gamma = (const float*)d_in[1];
    const float* beta  = (const float*)d_in[2];
    const void*  mask  = d_in[3];
    float* out = (float*)d_out;

    float* m01 = (float*)d_ws;       // Fn floats
    float* mg  = m01 + Fn;           // Fn floats

    prep_kernel<<<16, NT, 0, stream>>>(mask, gamma, m01, mg);
    dropnorm_kernel<<<Bn, NT, 0, stream>>>(x, m01, mg, beta, out);
}